// Round 9
// baseline (204.299 us; speedup 1.0000x reference)
//
#include <hip/hip_runtime.h>

#define BATCH 8192

// ---------------------------------------------------------------------------
// Kernel 1: per-sample fused conv1+pool+conv2+pool+v-dot+attention tail.
// One block = one sample, 256 threads. 2-dispatch structure: weight reorder
// done per-block into LDS (no prep kernel); BN stats/apply in bn_final.
// LDS plan (floats, lifetime-overlapped):
//   [0,3136)    xs[900] (conv1 input)  ∪  c2out[16][196] (conv2 out)
//   [3136,5440) p1t[256 pos][9]  (8 ic + 1 pad, odd stride => conflict-free)
//   [5440,6592) w2s[72][16] (conv2 weights, tap*8+ic major)  ∪  p2[784]
//   [6592,6608) vred[4][4]
// ---------------------------------------------------------------------------
__global__ __launch_bounds__(256, 4) void fused_fwd(
    const float* __restrict__ x,        // [B,1,28,28]
    const float* __restrict__ params,   // [B,4]
    const float* __restrict__ c1w,      // [8,1,3,3]
    const float* __restrict__ c1b,      // [8]
    const float* __restrict__ c2w,      // [16,8,3,3]
    const float* __restrict__ c2b,      // [16]
    const float* __restrict__ qkvw,     // [12,784]
    const float* __restrict__ qkvb,     // [12]
    const float* __restrict__ outw,     // [4,4]
    const float* __restrict__ outb,     // [4]
    float* __restrict__ pre)            // ws: [B,4] pre-BN
{
    __shared__ __align__(16) float lds[6608];
    float* xs    = lds;            // [900]
    float* c2out = lds;            // [16][196]
    float* p1t   = lds + 3136;     // [256][9]
    float* w2s   = lds + 5440;     // [72][16]
    float* p2    = lds + 5440;     // [784]
    float* vred  = lds + 6592;     // [4][4]

    const int tid = threadIdx.x;
    const int b = blockIdx.x;

    // ---- stage input (zero-padded 30x30) + zero p1t + reorder conv2 w ----
    for (int i = tid; i < 900; i += 256) {
        int h = i / 30, w = i - h * 30;
        float v = 0.f;
        if (h >= 1 && h <= 28 && w >= 1 && w <= 28)
            v = x[b * 784 + (h - 1) * 28 + (w - 1)];
        xs[i] = v;
    }
    for (int i = tid; i < 2304; i += 256) p1t[i] = 0.f;
    // w2s[(tap*8+ic)*16+oc] = c2w[oc*72+ic*9+tap]  (L2-hit after first blocks)
    for (int j = tid; j < 1152; j += 256) {
        int oc  = j & 15;
        int tic = j >> 4;       // 0..71
        int ic  = tic & 7;
        int tap = tic >> 3;     // 0..8 (dh*3+dw)
        w2s[j] = c2w[oc * 72 + ic * 9 + tap];
    }
    __syncthreads();

    // ---- conv1 (1->8) + relu + maxpool2: thread = pooled pos, 196 active ----
    {
        const int pos = tid < 196 ? tid : 195;   // clamp: uniform control flow
        const int ph = pos / 14, pw = pos - ph * 14;
        const float* base = &xs[(2 * ph) * 30 + 2 * pw];
        float in[4][4];
        #pragma unroll
        for (int r = 0; r < 4; ++r)
            #pragma unroll
            for (int c = 0; c < 4; ++c)
                in[r][c] = base[r * 30 + c];
        const int obase = ((ph + 1) * 16 + (pw + 1)) * 9;
        #pragma unroll
        for (int oc = 0; oc < 8; ++oc) {
            float m = 0.f;   // max(relu) == relu(max); relu floor is 0
            #pragma unroll
            for (int dh = 0; dh < 2; ++dh)
                #pragma unroll
                for (int dw = 0; dw < 2; ++dw) {
                    float a = c1b[oc];
                    #pragma unroll
                    for (int r = 0; r < 3; ++r)
                        #pragma unroll
                        for (int c = 0; c < 3; ++c)
                            a += in[dh + r][dw + c] * c1w[oc * 9 + r * 3 + c];
                    m = fmaxf(m, a);
                }
            if (tid < 196) p1t[obase + oc] = m;
        }
    }
    __syncthreads();   // also last read of xs before c2out overwrites it

    // ---- conv2 (8->16): thread = conv output pos (14x14), 16 oc in regs.
    // ROLLED (tap,ic) loop: 16 live weight floats/step via LDS broadcast
    // (round-4 lesson: full unroll => 1152 hoisted uniforms => spill storm).
    {
        const int pos = tid < 196 ? tid : 195;
        const int h = pos / 14, w = pos - h * 14;
        const int pbase = (h * 16 + w) * 9;

        float a0  = c2b[0],  a1  = c2b[1],  a2  = c2b[2],  a3  = c2b[3];
        float a4  = c2b[4],  a5  = c2b[5],  a6  = c2b[6],  a7  = c2b[7];
        float a8  = c2b[8],  a9  = c2b[9],  a10 = c2b[10], a11 = c2b[11];
        float a12 = c2b[12], a13 = c2b[13], a14 = c2b[14], a15 = c2b[15];

        const float* wp = w2s;
        #pragma unroll 1
        for (int dh = 0; dh < 3; ++dh) {
            #pragma unroll 1
            for (int dw = 0; dw < 3; ++dw) {
                const int ibase = pbase + (dh * 16 + dw) * 9;
                #pragma unroll 1
                for (int ic = 0; ic < 8; ++ic) {
                    const float iv = p1t[ibase + ic];
                    const float4 w0 = *(const float4*)(wp + 0);
                    const float4 w1 = *(const float4*)(wp + 4);
                    const float4 w2 = *(const float4*)(wp + 8);
                    const float4 w3 = *(const float4*)(wp + 12);
                    a0  += iv * w0.x;  a1  += iv * w0.y;
                    a2  += iv * w0.z;  a3  += iv * w0.w;
                    a4  += iv * w1.x;  a5  += iv * w1.y;
                    a6  += iv * w1.z;  a7  += iv * w1.w;
                    a8  += iv * w2.x;  a9  += iv * w2.y;
                    a10 += iv * w2.z;  a11 += iv * w2.w;
                    a12 += iv * w3.x;  a13 += iv * w3.y;
                    a14 += iv * w3.z;  a15 += iv * w3.w;
                    wp += 16;
                }
            }
        }
        if (tid < 196) {
            c2out[0  * 196 + pos] = fmaxf(a0,  0.f);
            c2out[1  * 196 + pos] = fmaxf(a1,  0.f);
            c2out[2  * 196 + pos] = fmaxf(a2,  0.f);
            c2out[3  * 196 + pos] = fmaxf(a3,  0.f);
            c2out[4  * 196 + pos] = fmaxf(a4,  0.f);
            c2out[5  * 196 + pos] = fmaxf(a5,  0.f);
            c2out[6  * 196 + pos] = fmaxf(a6,  0.f);
            c2out[7  * 196 + pos] = fmaxf(a7,  0.f);
            c2out[8  * 196 + pos] = fmaxf(a8,  0.f);
            c2out[9  * 196 + pos] = fmaxf(a9,  0.f);
            c2out[10 * 196 + pos] = fmaxf(a10, 0.f);
            c2out[11 * 196 + pos] = fmaxf(a11, 0.f);
            c2out[12 * 196 + pos] = fmaxf(a12, 0.f);
            c2out[13 * 196 + pos] = fmaxf(a13, 0.f);
            c2out[14 * 196 + pos] = fmaxf(a14, 0.f);
            c2out[15 * 196 + pos] = fmaxf(a15, 0.f);
        }
    }
    __syncthreads();   // also last read of w2s before p2 overwrites it

    // ---- maxpool2 -> p2 [16][7][7] ----
    for (int it = tid; it < 784; it += 256) {
        int c = it / 49, r = it - c * 49;
        int ph = r / 7, pw = r - ph * 7;
        const float* pb = &c2out[c * 196 + (2 * ph) * 14 + 2 * pw];
        p2[it] = fmaxf(fmaxf(pb[0], pb[1]), fmaxf(pb[14], pb[15]));
    }
    __syncthreads();

    // ---- v = p2 . qkv_w[8..11] (q,k provably unused), float4 ----
    float v0 = 0.f, v1 = 0.f, v2 = 0.f, v3 = 0.f;
    if (tid < 196) {
        float4 f  = *(const float4*)&p2[tid * 4];
        float4 a0 = ((const float4*)&qkvw[8 * 784])[tid];
        float4 a1 = ((const float4*)&qkvw[9 * 784])[tid];
        float4 a2 = ((const float4*)&qkvw[10 * 784])[tid];
        float4 a3 = ((const float4*)&qkvw[11 * 784])[tid];
        v0 = f.x * a0.x + f.y * a0.y + f.z * a0.z + f.w * a0.w;
        v1 = f.x * a1.x + f.y * a1.y + f.z * a1.z + f.w * a1.w;
        v2 = f.x * a2.x + f.y * a2.y + f.z * a2.z + f.w * a2.w;
        v3 = f.x * a3.x + f.y * a3.y + f.z * a3.z + f.w * a3.w;
    }
    #pragma unroll
    for (int off = 32; off > 0; off >>= 1) {
        v0 += __shfl_xor(v0, off);
        v1 += __shfl_xor(v1, off);
        v2 += __shfl_xor(v2, off);
        v3 += __shfl_xor(v3, off);
    }
    if ((tid & 63) == 0) {
        const int wv = tid >> 6;
        vred[wv * 4 + 0] = v0; vred[wv * 4 + 1] = v1;
        vred[wv * 4 + 2] = v2; vred[wv * 4 + 3] = v3;
    }
    __syncthreads();

    // ---- tail: 4 lanes, one output channel each ----
    if (tid < 4) {
        float vv[4];
        #pragma unroll
        for (int j = 0; j < 4; ++j)
            vv[j] = vred[0 + j] + vred[4 + j] + vred[8 + j] + vred[12 + j]
                  + qkvb[8 + j];

        float lg[4];
        float run = 1.f;
        #pragma unroll
        for (int j = 0; j < 4; ++j) { run *= cosf(params[b * 4 + j]); lg[j] = run; }
        float mx = fmaxf(fmaxf(lg[0], lg[1]), fmaxf(lg[2], lg[3]));
        float e[4], s = 0.f;
        #pragma unroll
        for (int j = 0; j < 4; ++j) { e[j] = expf(lg[j] - mx); s += e[j]; }
        float inv = 1.f / s;

        float t = outb[tid];
        #pragma unroll
        for (int j = 0; j < 4; ++j) t += outw[tid * 4 + j] * (e[j] * inv * vv[j]);
        pre[b * 4 + tid] = t;
    }
}

// ---------------------------------------------------------------------------
// Kernel 2: BN stats + apply in one kernel. 128 blocks x 256 threads.
// Each block redundantly reduces all of pre[8192] (float4/sample; 128 KB,
// L2-resident; 16 MB aggregate ~ 0.5 us) then applies BN to its 64 samples.
// ---------------------------------------------------------------------------
__global__ __launch_bounds__(256) void bn_final(
    const float* __restrict__ pre, const float* __restrict__ gamma,
    const float* __restrict__ beta, float* __restrict__ out)
{
    __shared__ float red[4][8];
    const int tid = threadIdx.x;
    const float4* pre4 = (const float4*)pre;

    float4 s = make_float4(0.f, 0.f, 0.f, 0.f);
    float4 q = make_float4(0.f, 0.f, 0.f, 0.f);
    for (int i = tid; i < 8192; i += 256) {
        float4 v = pre4[i];
        s.x += v.x; s.y += v.y; s.z += v.z; s.w += v.w;
        q.x += v.x * v.x; q.y += v.y * v.y; q.z += v.z * v.z; q.w += v.w * v.w;
    }
    #pragma unroll
    for (int off = 32; off > 0; off >>= 1) {
        s.x += __shfl_xor(s.x, off); s.y += __shfl_xor(s.y, off);
        s.z += __shfl_xor(s.z, off); s.w += __shfl_xor(s.w, off);
        q.x += __shfl_xor(q.x, off); q.y += __shfl_xor(q.y, off);
        q.z += __shfl_xor(q.z, off); q.w += __shfl_xor(q.w, off);
    }
    if ((tid & 63) == 0) {
        const int wv = tid >> 6;
        red[wv][0] = s.x; red[wv][1] = s.y; red[wv][2] = s.z; red[wv][3] = s.w;
        red[wv][4] = q.x; red[wv][5] = q.y; red[wv][6] = q.z; red[wv][7] = q.w;
    }
    __syncthreads();

    // every thread computes the 4-channel stats from the 4x8 partials
    float mu[4], inv[4];
    #pragma unroll
    for (int c = 0; c < 4; ++c) {
        float ts = red[0][c] + red[1][c] + red[2][c] + red[3][c];
        float tq = red[0][4 + c] + red[1][4 + c] + red[2][4 + c] + red[3][4 + c];
        float m = ts * (1.f / 8192.f);
        mu[c] = m;
        inv[c] = rsqrtf(tq * (1.f / 8192.f) - m * m + 1e-5f);
    }

    // apply to this block's 64 samples
    if (tid < 64) {
        const int i = blockIdx.x * 64 + tid;
        float4 v = pre4[i];
        float4 g = *(const float4*)gamma;
        float4 be = *(const float4*)beta;
        float4 o;
        o.x = (v.x - mu[0]) * inv[0] * g.x + be.x;
        o.y = (v.y - mu[1]) * inv[1] * g.y + be.y;
        o.z = (v.z - mu[2]) * inv[2] * g.z + be.z;
        o.w = (v.w - mu[3]) * inv[3] * g.w + be.w;
        ((float4*)out)[i] = o;
    }
}

extern "C" void kernel_launch(void* const* d_in, const int* in_sizes, int n_in,
                              void* d_out, int out_size, void* d_ws, size_t ws_size,
                              hipStream_t stream) {
    const float* x      = (const float*)d_in[0];
    const float* params = (const float*)d_in[1];
    const float* c1w    = (const float*)d_in[2];
    const float* c1b    = (const float*)d_in[3];
    const float* c2w    = (const float*)d_in[4];
    const float* c2b    = (const float*)d_in[5];
    const float* qkvw   = (const float*)d_in[6];
    const float* qkvb   = (const float*)d_in[7];
    const float* outw   = (const float*)d_in[8];
    const float* outb   = (const float*)d_in[9];
    const float* gamma  = (const float*)d_in[10];
    const float* beta   = (const float*)d_in[11];

    float* pre = (float*)d_ws;   // 32768 floats

    fused_fwd<<<BATCH, 256, 0, stream>>>(x, params, c1w, c1b, c2w, c2b,
                                         qkvw, qkvb, outw, outb, pre);
    bn_final<<<128, 256, 0, stream>>>(pre, gamma, beta, (float*)d_out);
}

// Round 11
// 178.201 us; speedup vs baseline: 1.1464x; 1.1464x over previous
//
#include <hip/hip_runtime.h>

#define BATCH 8192

typedef __fp16 h2 __attribute__((ext_vector_type(2)));
union H2U { unsigned u; h2 h; };
__device__ __forceinline__ h2 asH2(unsigned v) { H2U t; t.u = v; return t.h; }

// ---------------------------------------------------------------------------
// Kernel 0: prep — pack conv2 weights [16oc][8ic][3][3] into half2:
// w2h[(tap*4+icp)*16 + oc] = (c2w[oc][2*icp][tap], c2w[oc][2*icp+1][tap])
// 16 consecutive uints per (tap,icp) step => 4 uniform uint4 s_loads.
// ---------------------------------------------------------------------------
__global__ __launch_bounds__(256) void prep(const float* __restrict__ c2w,
                                            unsigned* __restrict__ w2h) {
    int i = blockIdx.x * 256 + threadIdx.x;
    if (i < 576) {
        int oc  = i & 15;
        int t   = i >> 4;      // 0..35 = tap*4 + icp
        int icp = t & 3;
        int tap = t >> 2;      // dh*3+dw
        float lo = c2w[oc * 72 + (2 * icp) * 9 + tap];
        float hi = c2w[oc * 72 + (2 * icp + 1) * 9 + tap];
        H2U u; u.h = __builtin_amdgcn_cvt_pkrtz(lo, hi);
        w2h[i] = u.u;
    }
}

// ---------------------------------------------------------------------------
// Kernel 1: per-sample fused conv1+pool+conv2(fp16 dot2)+pool+v-dot+tail.
// One block = one sample, 256 threads.
// LDS (floats, lifetime-overlapped), 5216 f = 20.4 KB => 7 blocks/CU:
//   [0,3136)    xs[900] (conv1 in) ∪ c2out[16][196] (conv2 out)
//   [3136,4416) p1h: uint[256 pos][5] (4 half2 = 8 ic, +1 pad => stride 5 odd)
//   [4416,5200) p2[784]
//   [5200,5216) vred[4][4]
// Weights: conv1 fp32 + conv2 half2 both via wave-uniform GLOBAL loads
// (round-9 lesson: LDS-broadcast weights cost +24us vs scalarized global).
// conv2 loop ROLLED at icp level: 16 live weight uints/step (round-4 lesson:
// full unroll => ~1152 hoisted uniforms => AGPR spill storm).
// ---------------------------------------------------------------------------
__global__ __launch_bounds__(256, 4) void fused_fwd(
    const float* __restrict__ x,        // [B,1,28,28]
    const float* __restrict__ params,   // [B,4]
    const float* __restrict__ c1w,      // [8,1,3,3]
    const float* __restrict__ c1b,      // [8]
    const float* __restrict__ c2b,      // [16]
    const float* __restrict__ qkvw,     // [12,784]
    const float* __restrict__ qkvb,     // [12]
    const float* __restrict__ outw,     // [4,4]
    const float* __restrict__ outb,     // [4]
    const unsigned* __restrict__ w2h,   // [36][16] half2-packed conv2 weights
    float* __restrict__ pre)            // ws: [B,4] pre-BN
{
    __shared__ __align__(16) float lds[5216];
    float*    xs    = lds;                          // [900]
    float*    c2out = lds;                          // [16][196]
    unsigned* p1h   = (unsigned*)(lds + 3136);      // [256][5]
    float*    p2    = lds + 4416;                   // [784]
    float*    vred  = lds + 5200;                   // [16]

    const int tid = threadIdx.x;
    const int b = blockIdx.x;

    // ---- stage input (zero-padded 30x30) + zero p1h ----
    for (int i = tid; i < 900; i += 256) {
        int h = i / 30, w = i - h * 30;
        float v = 0.f;
        if (h >= 1 && h <= 28 && w >= 1 && w <= 28)
            v = x[b * 784 + (h - 1) * 28 + (w - 1)];
        xs[i] = v;
    }
    for (int i = tid; i < 1280; i += 256) p1h[i] = 0u;
    __syncthreads();

    // ---- conv1 (1->8) + relu + maxpool2 -> p1h half2-packed ----
    {
        const int pos = tid < 196 ? tid : 195;   // clamp: uniform control flow
        const int ph = pos / 14, pw = pos - ph * 14;
        const float* base = &xs[(2 * ph) * 30 + 2 * pw];
        float in[4][4];
        #pragma unroll
        for (int r = 0; r < 4; ++r)
            #pragma unroll
            for (int c = 0; c < 4; ++c)
                in[r][c] = base[r * 30 + c];
        float o[8];
        #pragma unroll
        for (int oc = 0; oc < 8; ++oc) {
            float m = 0.f;   // max(relu) == relu(max); relu floor is 0
            #pragma unroll
            for (int dh = 0; dh < 2; ++dh)
                #pragma unroll
                for (int dw = 0; dw < 2; ++dw) {
                    float a = c1b[oc];
                    #pragma unroll
                    for (int r = 0; r < 3; ++r)
                        #pragma unroll
                        for (int c = 0; c < 3; ++c)
                            a += in[dh + r][dw + c] * c1w[oc * 9 + r * 3 + c];
                    m = fmaxf(m, a);
                }
            o[oc] = m;
        }
        if (tid < 196) {
            const int obase = ((ph + 1) * 16 + (pw + 1)) * 5;
            H2U u0, u1, u2, u3;
            u0.h = __builtin_amdgcn_cvt_pkrtz(o[0], o[1]);
            u1.h = __builtin_amdgcn_cvt_pkrtz(o[2], o[3]);
            u2.h = __builtin_amdgcn_cvt_pkrtz(o[4], o[5]);
            u3.h = __builtin_amdgcn_cvt_pkrtz(o[6], o[7]);
            p1h[obase + 0] = u0.u;
            p1h[obase + 1] = u1.u;
            p1h[obase + 2] = u2.u;
            p1h[obase + 3] = u3.u;
        }
    }
    __syncthreads();   // also last read of xs before c2out overwrites it

    // ---- conv2 (8->16) via v_dot2_f32_f16: 36 steps x 16 dot2 ----
    {
        const int pos = tid < 196 ? tid : 195;
        const int h = pos / 14, w = pos - h * 14;

        float a0  = c2b[0],  a1  = c2b[1],  a2  = c2b[2],  a3  = c2b[3];
        float a4  = c2b[4],  a5  = c2b[5],  a6  = c2b[6],  a7  = c2b[7];
        float a8  = c2b[8],  a9  = c2b[9],  a10 = c2b[10], a11 = c2b[11];
        float a12 = c2b[12], a13 = c2b[13], a14 = c2b[14], a15 = c2b[15];

        const uint4* wp = (const uint4*)w2h;
        #pragma unroll 1
        for (int dh = 0; dh < 3; ++dh) {
            #pragma unroll 1
            for (int dw = 0; dw < 3; ++dw) {
                const int ibase = ((h + dh) * 16 + (w + dw)) * 5;
                #pragma unroll 1
                for (int icp = 0; icp < 4; ++icp) {
                    const h2 iv = asH2(p1h[ibase + icp]);
                    const uint4 wA = wp[0];
                    const uint4 wB = wp[1];
                    const uint4 wC = wp[2];
                    const uint4 wD = wp[3];
                    a0  = __builtin_amdgcn_fdot2(iv, asH2(wA.x), a0,  false);
                    a1  = __builtin_amdgcn_fdot2(iv, asH2(wA.y), a1,  false);
                    a2  = __builtin_amdgcn_fdot2(iv, asH2(wA.z), a2,  false);
                    a3  = __builtin_amdgcn_fdot2(iv, asH2(wA.w), a3,  false);
                    a4  = __builtin_amdgcn_fdot2(iv, asH2(wB.x), a4,  false);
                    a5  = __builtin_amdgcn_fdot2(iv, asH2(wB.y), a5,  false);
                    a6  = __builtin_amdgcn_fdot2(iv, asH2(wB.z), a6,  false);
                    a7  = __builtin_amdgcn_fdot2(iv, asH2(wB.w), a7,  false);
                    a8  = __builtin_amdgcn_fdot2(iv, asH2(wC.x), a8,  false);
                    a9  = __builtin_amdgcn_fdot2(iv, asH2(wC.y), a9,  false);
                    a10 = __builtin_amdgcn_fdot2(iv, asH2(wC.z), a10, false);
                    a11 = __builtin_amdgcn_fdot2(iv, asH2(wC.w), a11, false);
                    a12 = __builtin_amdgcn_fdot2(iv, asH2(wD.x), a12, false);
                    a13 = __builtin_amdgcn_fdot2(iv, asH2(wD.y), a13, false);
                    a14 = __builtin_amdgcn_fdot2(iv, asH2(wD.z), a14, false);
                    a15 = __builtin_amdgcn_fdot2(iv, asH2(wD.w), a15, false);
                    wp += 4;
                }
            }
        }
        if (tid < 196) {
            c2out[0  * 196 + pos] = fmaxf(a0,  0.f);
            c2out[1  * 196 + pos] = fmaxf(a1,  0.f);
            c2out[2  * 196 + pos] = fmaxf(a2,  0.f);
            c2out[3  * 196 + pos] = fmaxf(a3,  0.f);
            c2out[4  * 196 + pos] = fmaxf(a4,  0.f);
            c2out[5  * 196 + pos] = fmaxf(a5,  0.f);
            c2out[6  * 196 + pos] = fmaxf(a6,  0.f);
            c2out[7  * 196 + pos] = fmaxf(a7,  0.f);
            c2out[8  * 196 + pos] = fmaxf(a8,  0.f);
            c2out[9  * 196 + pos] = fmaxf(a9,  0.f);
            c2out[10 * 196 + pos] = fmaxf(a10, 0.f);
            c2out[11 * 196 + pos] = fmaxf(a11, 0.f);
            c2out[12 * 196 + pos] = fmaxf(a12, 0.f);
            c2out[13 * 196 + pos] = fmaxf(a13, 0.f);
            c2out[14 * 196 + pos] = fmaxf(a14, 0.f);
            c2out[15 * 196 + pos] = fmaxf(a15, 0.f);
        }
    }
    __syncthreads();

    // ---- maxpool2 -> p2 [16][7][7] ----
    for (int it = tid; it < 784; it += 256) {
        int c = it / 49, r = it - c * 49;
        int ph = r / 7, pw = r - ph * 7;
        const float* pb = &c2out[c * 196 + (2 * ph) * 14 + 2 * pw];
        p2[it] = fmaxf(fmaxf(pb[0], pb[1]), fmaxf(pb[14], pb[15]));
    }
    __syncthreads();

    // ---- v = p2 . qkv_w[8..11] (q,k provably unused), float4 ----
    float v0 = 0.f, v1 = 0.f, v2 = 0.f, v3 = 0.f;
    if (tid < 196) {
        float4 f  = *(const float4*)&p2[tid * 4];
        float4 a0 = ((const float4*)&qkvw[8 * 784])[tid];
        float4 a1 = ((const float4*)&qkvw[9 * 784])[tid];
        float4 a2 = ((const float4*)&qkvw[10 * 784])[tid];
        float4 a3 = ((const float4*)&qkvw[11 * 784])[tid];
        v0 = f.x * a0.x + f.y * a0.y + f.z * a0.z + f.w * a0.w;
        v1 = f.x * a1.x + f.y * a1.y + f.z * a1.z + f.w * a1.w;
        v2 = f.x * a2.x + f.y * a2.y + f.z * a2.z + f.w * a2.w;
        v3 = f.x * a3.x + f.y * a3.y + f.z * a3.z + f.w * a3.w;
    }
    #pragma unroll
    for (int off = 32; off > 0; off >>= 1) {
        v0 += __shfl_xor(v0, off);
        v1 += __shfl_xor(v1, off);
        v2 += __shfl_xor(v2, off);
        v3 += __shfl_xor(v3, off);
    }
    if ((tid & 63) == 0) {
        const int wv = tid >> 6;
        vred[wv * 4 + 0] = v0; vred[wv * 4 + 1] = v1;
        vred[wv * 4 + 2] = v2; vred[wv * 4 + 3] = v3;
    }
    __syncthreads();

    // ---- tail: 4 lanes, one output channel each ----
    if (tid < 4) {
        float vv[4];
        #pragma unroll
        for (int j = 0; j < 4; ++j)
            vv[j] = vred[0 + j] + vred[4 + j] + vred[8 + j] + vred[12 + j]
                  + qkvb[8 + j];

        float lg[4];
        float run = 1.f;
        #pragma unroll
        for (int j = 0; j < 4; ++j) { run *= cosf(params[b * 4 + j]); lg[j] = run; }
        float mx = fmaxf(fmaxf(lg[0], lg[1]), fmaxf(lg[2], lg[3]));
        float e[4], s = 0.f;
        #pragma unroll
        for (int j = 0; j < 4; ++j) { e[j] = expf(lg[j] - mx); s += e[j]; }
        float inv = 1.f / s;

        float t = outb[tid];
        #pragma unroll
        for (int j = 0; j < 4; ++j) t += outw[tid * 4 + j] * (e[j] * inv * vv[j]);
        pre[b * 4 + tid] = t;
    }
}

// ---------------------------------------------------------------------------
// Kernel 2: BN stats + apply. 128 blocks x 256 threads; each block
// redundantly reduces L2-resident pre[8192x4] then applies to its 64 samples.
// ---------------------------------------------------------------------------
__global__ __launch_bounds__(256) void bn_final(
    const float* __restrict__ pre, const float* __restrict__ gamma,
    const float* __restrict__ beta, float* __restrict__ out)
{
    __shared__ float red[4][8];
    const int tid = threadIdx.x;
    const float4* pre4 = (const float4*)pre;

    float4 s = make_float4(0.f, 0.f, 0.f, 0.f);
    float4 q = make_float4(0.f, 0.f, 0.f, 0.f);
    for (int i = tid; i < 8192; i += 256) {
        float4 v = pre4[i];
        s.x += v.x; s.y += v.y; s.z += v.z; s.w += v.w;
        q.x += v.x * v.x; q.y += v.y * v.y; q.z += v.z * v.z; q.w += v.w * v.w;
    }
    #pragma unroll
    for (int off = 32; off > 0; off >>= 1) {
        s.x += __shfl_xor(s.x, off); s.y += __shfl_xor(s.y, off);
        s.z += __shfl_xor(s.z, off); s.w += __shfl_xor(s.w, off);
        q.x += __shfl_xor(q.x, off); q.y += __shfl_xor(q.y, off);
        q.z += __shfl_xor(q.z, off); q.w += __shfl_xor(q.w, off);
    }
    if ((tid & 63) == 0) {
        const int wv = tid >> 6;
        red[wv][0] = s.x; red[wv][1] = s.y; red[wv][2] = s.z; red[wv][3] = s.w;
        red[wv][4] = q.x; red[wv][5] = q.y; red[wv][6] = q.z; red[wv][7] = q.w;
    }
    __syncthreads();

    float mu[4], inv[4];
    #pragma unroll
    for (int c = 0; c < 4; ++c) {
        float ts = red[0][c] + red[1][c] + red[2][c] + red[3][c];
        float tq = red[0][4 + c] + red[1][4 + c] + red[2][4 + c] + red[3][4 + c];
        float m = ts * (1.f / 8192.f);
        mu[c] = m;
        inv[c] = rsqrtf(tq * (1.f / 8192.f) - m * m + 1e-5f);
    }

    if (tid < 64) {
        const int i = blockIdx.x * 64 + tid;
        float4 v = pre4[i];
        float4 g  = *(const float4*)gamma;
        float4 be = *(const float4*)beta;
        float4 o;
        o.x = (v.x - mu[0]) * inv[0] * g.x + be.x;
        o.y = (v.y - mu[1]) * inv[1] * g.y + be.y;
        o.z = (v.z - mu[2]) * inv[2] * g.z + be.z;
        o.w = (v.w - mu[3]) * inv[3] * g.w + be.w;
        ((float4*)out)[i] = o;
    }
}

extern "C" void kernel_launch(void* const* d_in, const int* in_sizes, int n_in,
                              void* d_out, int out_size, void* d_ws, size_t ws_size,
                              hipStream_t stream) {
    const float* x      = (const float*)d_in[0];
    const float* params = (const float*)d_in[1];
    const float* c1w    = (const float*)d_in[2];
    const float* c1b    = (const float*)d_in[3];
    const float* c2w    = (const float*)d_in[4];
    const float* c2b    = (const float*)d_in[5];
    const float* qkvw   = (const float*)d_in[6];
    const float* qkvb   = (const float*)d_in[7];
    const float* outw   = (const float*)d_in[8];
    const float* outb   = (const float*)d_in[9];
    const float* gamma  = (const float*)d_in[10];
    const float* beta   = (const float*)d_in[11];

    unsigned* w2h = (unsigned*)d_ws;            // 576 uints
    float*    pre = (float*)d_ws + 1024;        // 32768 floats (16B-aligned)

    prep<<<3, 256, 0, stream>>>(c2w, w2h);
    fused_fwd<<<BATCH, 256, 0, stream>>>(x, params, c1w, c1b, c2b,
                                         qkvw, qkvb, outw, outb, w2h, pre);
    bn_final<<<128, 256, 0, stream>>>(pre, gamma, beta, (float*)d_out);
}